// Round 6
// baseline (63.341 us; speedup 1.0000x reference)
//
#include <hip/hip_runtime.h>
#include <hip/hip_bf16.h>

// ConvMosaic via bf16 MFMA.
// y[n,co,h,w] = sum_{c,di,dj} x[n,c,h+di-1,w+dj-1] * W[w%16, c*9+di*3+dj, co]
// K reordered as k' = tap*32 + c (tap = di*3+dj) so one MFMA K=32 step == one tap.
// v6: double-buffered B-fragment prefetch pinned with sched_barrier(0) —
//     the compiler otherwise sinks loads to uses (round-5 VGPR=32) and
//     serializes 36 x ~250cyc L2 loads per thread.

using bf16 = __hip_bfloat16;
typedef __attribute__((ext_vector_type(8))) short bf16x8_t;  // A/B frag: 8 bf16 (4 VGPR)
typedef __attribute__((ext_vector_type(4))) float f32x4_t;   // C/D frag

constexpr int NB    = 4;
constexpr int C_IN  = 32;
constexpr int HH    = 256;
constexpr int WW    = 256;
constexpr int C_OUT = 64;
constexpr int SPE   = 16;

constexpr int TH = 16;          // tile height (== MFMA M)
constexpr int TW = 32;          // tile width (w and w+16 share s = w%16)
constexpr int XR = TH + 2;      // 18
constexpr int XC = TW + 2;      // 34
constexpr int CPAD = 40;        // c-dim padded 32->40: 80 B row stride (16B-aligned)

// ---- pre-pass: W[s][c*9+tap][co] f32 -> W_t[s][co][tap*32+c] bf16 ----
__global__ __launch_bounds__(256)
void prep_weights(const float* __restrict__ w, bf16* __restrict__ wt) {
    int idx = blockIdx.x * 256 + threadIdx.x;  // 16*64*288 total
    if (idx >= SPE * C_OUT * 288) return;
    int s  = idx / (C_OUT * 288);
    int r  = idx % (C_OUT * 288);
    int co = r / 288;
    int kk = r % 288;            // kk = tap*32 + c
    int tap = kk >> 5;
    int c   = kk & 31;
    float v = w[((size_t)s * 288 + c * 9 + tap) * C_OUT + co];
    wt[idx] = __float2bfloat16(v);
}

// Issue one si's 9 B-fragments as a batch, then fence so the scheduler
// cannot sink them into / below the following compute.
#define LOADB(B, SI)                                                          \
    {                                                                         \
        const bf16* bp = wt + ((size_t)((g * 4 + (SI)) * C_OUT + ct * 16 + lm) * 288 + lg * 8); \
        _Pragma("unroll")                                                     \
        for (int tap = 0; tap < 9; ++tap)                                     \
            B[tap] = *reinterpret_cast<const bf16x8_t*>(bp + tap * 32);       \
    }                                                                         \
    __builtin_amdgcn_sched_barrier(0);

#define COMPUTE(B, SI)                                                        \
    {                                                                         \
        const bf16* ap = &xs[(lm * XC + g * 4 + (SI)) * CPAD + lg * 8];       \
        _Pragma("unroll")                                                     \
        for (int tap = 0; tap < 9; ++tap) {                                   \
            const int di = tap / 3, dj = tap % 3;                             \
            bf16x8_t a0 = *reinterpret_cast<const bf16x8_t*>(ap + (di * XC + dj) * CPAD);      \
            bf16x8_t a1 = *reinterpret_cast<const bf16x8_t*>(ap + (di * XC + dj + 16) * CPAD); \
            dacc[0][SI] = __builtin_amdgcn_mfma_f32_16x16x32_bf16(a0, B[tap], dacc[0][SI], 0, 0, 0); \
            dacc[1][SI] = __builtin_amdgcn_mfma_f32_16x16x32_bf16(a1, B[tap], dacc[1][SI], 0, 0, 0); \
        }                                                                     \
    }

__global__ __launch_bounds__(1024, 4)
void conv_mosaic_mfma(const float* __restrict__ x,
                      const bf16* __restrict__ wt,
                      float* __restrict__ out) {
    __shared__ __align__(16) bf16 xs[XR * XC * CPAD];  // 18*34*40*2 = 48960 B

    const int n  = blockIdx.y;
    const int tw = blockIdx.x & 7;    // 8 w-tiles
    const int th = blockIdx.x >> 3;   // 16 h-tiles
    const int h0 = th * TH;
    const int w0 = tw * TW;
    const int t  = threadIdx.x;

    // 16 waves: wave = s-group (wave&3) x c_out tile (wave>>2)
    const int wave = t >> 6;
    const int lane = t & 63;
    const int g    = wave & 3;    // s = g*4 + si
    const int ct   = wave >> 2;   // co tile: co = ct*16 + lm
    const int lm   = lane & 15;   // A: row m (h). B/D: col n (co).
    const int lg   = lane >> 4;   // k-group; D row group

    // ---- stage x tile (zero-padded halo), f32 -> bf16, layout [row][col][c] ----
    const float* xn = x + (size_t)n * C_IN * HH * WW;
    constexpr int VJOBS = C_IN * XR * 8;  // 4608
#pragma unroll
    for (int it = 0; it < 5; ++it) {
        const int idx = t + it * 1024;
        if (idx < VJOBS) {
            const int c  = idx / (XR * 8);
            const int rr = idx % (XR * 8);
            const int r  = rr >> 3;
            const int q  = rr & 7;
            const int gh = h0 + r - 1;
            float4 v = make_float4(0.f, 0.f, 0.f, 0.f);
            if (gh >= 0 && gh < HH)
                v = *reinterpret_cast<const float4*>(
                    &xn[((size_t)c * HH + gh) * WW + w0 + q * 4]);
            bf16* d = &xs[(r * XC + q * 4 + 1) * CPAD + c];
            d[0]        = __float2bfloat16(v.x);
            d[CPAD]     = __float2bfloat16(v.y);
            d[2 * CPAD] = __float2bfloat16(v.z);
            d[3 * CPAD] = __float2bfloat16(v.w);
        }
    }
    // halo edge cols 0 and 33 (scalar, bounds-checked in h and w)
    constexpr int EJOBS = C_IN * XR * 2;  // 1152
#pragma unroll
    for (int it = 0; it < 2; ++it) {
        const int idx = t + it * 1024;
        if (idx < EJOBS) {
            const int c   = idx / (XR * 2);
            const int rr  = idx % (XR * 2);
            const int r   = rr >> 1;
            const int e   = rr & 1;
            const int col = e ? 33 : 0;
            const int gh  = h0 + r - 1;
            const int gw  = w0 + (e ? 32 : -1);
            float vv = 0.f;
            if (gh >= 0 && gh < HH && gw >= 0 && gw < WW)
                vv = xn[((size_t)c * HH + gh) * WW + gw];
            xs[(r * XC + col) * CPAD + c] = __float2bfloat16(vv);
        }
    }

    // persistent accumulators: [wm][si], si packs 4 consecutive w
    f32x4_t dacc[2][4];
#pragma unroll
    for (int b = 0; b < 2; ++b)
#pragma unroll
        for (int c = 0; c < 4; ++c) dacc[b][c] = (f32x4_t){0.f, 0.f, 0.f, 0.f};

    // B-fragment double buffers; first two batches issued before the barrier
    // so their L2 latency hides under the staging drain.
    bf16x8_t bA[9], bB[9];
    LOADB(bA, 0)
    LOADB(bB, 1)

    __syncthreads();

    COMPUTE(bA, 0)
    LOADB(bA, 2)
    COMPUTE(bB, 1)
    LOADB(bB, 3)
    COMPUTE(bA, 2)
    COMPUTE(bB, 3)

    // ---- store: float4 across si (4 consecutive w) ----
    const int co = ct * 16 + lm;
#pragma unroll
    for (int wm = 0; wm < 2; ++wm) {
#pragma unroll
        for (int j = 0; j < 4; ++j) {
            const int h = h0 + lg * 4 + j;
            float4 v = make_float4(dacc[wm][0][j], dacc[wm][1][j],
                                   dacc[wm][2][j], dacc[wm][3][j]);
            *reinterpret_cast<float4*>(
                &out[(((size_t)n * C_OUT + co) * HH + h) * WW + w0 + g * 4 + wm * 16]) = v;
        }
    }
}

extern "C" void kernel_launch(void* const* d_in, const int* in_sizes, int n_in,
                              void* d_out, int out_size, void* d_ws, size_t ws_size,
                              hipStream_t stream) {
    const float* x = (const float*)d_in[0];
    const float* w = (const float*)d_in[1];
    float* out     = (float*)d_out;
    bf16* wt       = (bf16*)d_ws;   // needs 16*64*288*2 = 589824 B

    prep_weights<<<(SPE * C_OUT * 288 + 255) / 256, 256, 0, stream>>>(w, wt);

    dim3 grid((WW / TW) * (HH / TH), NB);  // (8*16, 4) = 512 blocks
    conv_mosaic_mfma<<<grid, 1024, 0, stream>>>(x, wt, out);
}